// Round 1
// baseline (3243.732 us; speedup 1.0000x reference)
//
#include <hip/hip_runtime.h>
#include <hip/hip_bf16.h>
#include <cstdint>

// ReportDecoder: B=512,S=49,E=1024,H=1024,V2=16,L=64,T=48, D_IN=1105
// Strategy: precompute time-invariant xconst = im@Wimg^T + vp@Wvp^T + b_ih + b_hh.
// Per step: gates = h@Whh^T + lab@Wlab^T + xconst (+begin col at t==0) -> fused LSTM cell;
// then out = h_new@fc_w^T with fused activations + mask. bf16 MFMA, fp32 accum.

typedef __bf16 bf16_t;
typedef bf16_t bf16x8 __attribute__((ext_vector_type(8)));
typedef bf16_t bf16x4 __attribute__((ext_vector_type(4)));
typedef float  f32x4  __attribute__((ext_vector_type(4)));

#define Bn   512
#define Sn   49
#define En   1024
#define Hn   1024
#define Ln   64
#define Tn   48
#define DINn 1105
#define NOn  1090

#define BM   64
#define LDSP 72   // padded LDS K-stride (bf16 elems): 144B rows, 16B-aligned, 2-way bank alias (free)

__device__ __forceinline__ float sigm(float x){ return 1.0f / (1.0f + __expf(-x)); }

// ---------- image mean ----------
__global__ __launch_bounds__(256) void k_mean(const float* __restrict__ image,
                                              bf16_t* __restrict__ imb){
  int b  = blockIdx.x;
  int e0 = threadIdx.x * 4;
  const float* p = image + (size_t)b * (Sn * En) + e0;
  float4 acc = make_float4(0.f, 0.f, 0.f, 0.f);
  for (int s = 0; s < Sn; ++s){
    float4 v = *reinterpret_cast<const float4*>(p + (size_t)s * En);
    acc.x += v.x; acc.y += v.y; acc.z += v.z; acc.w += v.w;
  }
  const float inv = 1.0f / 49.0f;
  bf16x4 o;
  o[0] = (bf16_t)(acc.x * inv); o[1] = (bf16_t)(acc.y * inv);
  o[2] = (bf16_t)(acc.z * inv); o[3] = (bf16_t)(acc.w * inv);
  *reinterpret_cast<bf16x4*>(imb + (size_t)b * En + e0) = o;
}

// ---------- fp32 -> bf16 conversions (weights + label), one grid-stride kernel ----------
__global__ __launch_bounds__(256) void k_convert(
    const float* __restrict__ w_hh,  const float* __restrict__ fc_h_w,
    const float* __restrict__ fc_m_w,const float* __restrict__ fc_w,
    const float* __restrict__ label, const float* __restrict__ w_ih,
    bf16_t* __restrict__ whhb,  bf16_t* __restrict__ fchwb,
    bf16_t* __restrict__ fcmwb, bf16_t* __restrict__ fcwb,
    bf16_t* __restrict__ labelb,bf16_t* __restrict__ wimgb,
    bf16_t* __restrict__ wlabb){
  const int NV0 = 4096 * 1024 / 4;           // whh (vec4)
  const int NV1 = NV0 + 1024 * 1024 / 4;     // fc_h_w
  const int NV2 = NV1 + 1024 * 1024 / 4;     // fc_m_w
  const int NV3 = NV2 + 1090 * 1024 / 4;     // fc_w
  const int NV4 = NV3 + 512 * 49 * 64 / 4;   // label
  const int NS5 = NV4 + 4096 * 1024;         // wimg (scalar, strided src)
  const int NS6 = NS5 + 4096 * 64;           // wlab (scalar, strided src)
  int stride = gridDim.x * blockDim.x;
  for (int i = blockIdx.x * blockDim.x + threadIdx.x; i < NS6; i += stride){
    if (i < NV4){
      const float* src; bf16_t* dst; int j;
      if      (i < NV0){ src = w_hh;   dst = whhb;  j = i; }
      else if (i < NV1){ src = fc_h_w; dst = fchwb; j = i - NV0; }
      else if (i < NV2){ src = fc_m_w; dst = fcmwb; j = i - NV1; }
      else if (i < NV3){ src = fc_w;   dst = fcwb;  j = i - NV2; }
      else             { src = label;  dst = labelb;j = i - NV3; }
      float4 v = *reinterpret_cast<const float4*>(src + (size_t)j * 4);
      bf16x4 o;
      o[0] = (bf16_t)v.x; o[1] = (bf16_t)v.y; o[2] = (bf16_t)v.z; o[3] = (bf16_t)v.w;
      *reinterpret_cast<bf16x4*>(dst + (size_t)j * 4) = o;
    } else if (i < NS5){
      int j = i - NV4; int n = j >> 10, k = j & 1023;
      wimgb[j] = (bf16_t)w_ih[(size_t)n * DINn + k];
    } else {
      int j = i - NS5; int n = j >> 6, k = j & 63;
      wlabb[j] = (bf16_t)w_ih[(size_t)n * DINn + 1041 + k];
    }
  }
}

// ---------- xconst pre-pass: bias + view_position dot (fp32, exact) ----------
__global__ __launch_bounds__(256) void k_vpc(const float* __restrict__ w_ih,
                                             const float* __restrict__ vp,
                                             const float* __restrict__ b_ih,
                                             const float* __restrict__ b_hh,
                                             float* __restrict__ xconst){
  int idx = blockIdx.x * 256 + threadIdx.x;   // idx = b*4096 + n
  int b = idx >> 12, n = idx & 4095;
  float acc = b_ih[n] + b_hh[n];
  const float* w = w_ih + (size_t)n * DINn + En;
  const float* v = vp + b * 16;
  #pragma unroll
  for (int j = 0; j < 16; ++j) acc += v[j] * w[j];
  xconst[idx] = acc;
}

// ---------- shared GEMM helpers (64x128 tile, 4 waves 1x4, 16x16x32 bf16 MFMA) ----------
__device__ __forceinline__ void stageA(bf16_t* sA, const bf16_t* gptr, int ld, int tid){
  #pragma unroll
  for (int i = 0; i < 2; ++i){
    int idx = tid + i * 256;
    int r = idx >> 3, v = idx & 7;
    *reinterpret_cast<bf16x8*>(sA + r * LDSP + v * 8) =
      *reinterpret_cast<const bf16x8*>(gptr + (size_t)r * ld + v * 8);
  }
}

__device__ __forceinline__ void mma_tile(const bf16_t* sA, const bf16_t* sB,
                                         f32x4 (&acc)[4][2], int lane, int w){
  int lr = lane & 15;
  int lk = (lane >> 4) * 8;
  #pragma unroll
  for (int kk = 0; kk < 2; ++kk){
    bf16x8 a[4], bb[2];
    #pragma unroll
    for (int mi = 0; mi < 4; ++mi)
      a[mi] = *reinterpret_cast<const bf16x8*>(sA + (mi * 16 + lr) * LDSP + kk * 32 + lk);
    #pragma unroll
    for (int ni = 0; ni < 2; ++ni)
      bb[ni] = *reinterpret_cast<const bf16x8*>(sB + (w * 32 + ni * 16 + lr) * LDSP + kk * 32 + lk);
    #pragma unroll
    for (int mi = 0; mi < 4; ++mi)
      #pragma unroll
      for (int ni = 0; ni < 2; ++ni)
        acc[mi][ni] = __builtin_amdgcn_mfma_f32_16x16x32_bf16(a[mi], bb[ni], acc[mi][ni], 0, 0, 0);
  }
}

// ---------- init GEMM: h0 (tanh->bf16), m0 (tanh->f32), xconst += im@Wimg^T ----------
__global__ __launch_bounds__(256) void k_init_gemm(
    const bf16_t* __restrict__ imb,  const bf16_t* __restrict__ fchw,
    const bf16_t* __restrict__ fcmw, const bf16_t* __restrict__ wimg,
    const float* __restrict__ fc_h_b,const float* __restrict__ fc_m_b,
    bf16_t* __restrict__ h0, float* __restrict__ m0, float* __restrict__ xconst){
  __shared__ __align__(16) unsigned char smem[(BM + 128) * LDSP * 2];
  bf16_t* sA = (bf16_t*)smem;
  bf16_t* sB = (bf16_t*)(smem + BM * LDSP * 2);
  int tid = threadIdx.x;
  int cb = blockIdx.x, rb = blockIdx.y;
  int nBase = cb * 128;
  const bf16_t* Bsrc; int nOff;
  if      (nBase < 1024){ Bsrc = fchw; nOff = nBase; }
  else if (nBase < 2048){ Bsrc = fcmw; nOff = nBase - 1024; }
  else                  { Bsrc = wimg; nOff = nBase - 2048; }

  f32x4 acc[4][2] = {};
  int lane = tid & 63, w = tid >> 6;
  for (int kt = 0; kt < 16; ++kt){
    stageA(sA, imb + (size_t)(rb * 64) * 1024 + kt * 64, 1024, tid);
    #pragma unroll
    for (int i = 0; i < 4; ++i){
      int idx = tid + i * 256;
      int r = idx >> 3, v = idx & 7;
      *reinterpret_cast<bf16x8*>(sB + r * LDSP + v * 8) =
        *reinterpret_cast<const bf16x8*>(Bsrc + (size_t)(nOff + r) * 1024 + kt * 64 + v * 8);
    }
    __syncthreads();
    mma_tile(sA, sB, acc, lane, w);
    __syncthreads();
  }
  int lr = lane & 15, lg = lane >> 4;
  #pragma unroll
  for (int mi = 0; mi < 4; ++mi)
    #pragma unroll
    for (int ni = 0; ni < 2; ++ni)
      #pragma unroll
      for (int r = 0; r < 4; ++r){
        int ng   = nBase + w * 32 + ni * 16 + lr;
        int rowg = rb * 64 + mi * 16 + lg * 4 + r;
        float v = acc[mi][ni][r];
        if (ng < 1024){
          h0[(size_t)rowg * 1024 + ng] = (bf16_t)tanhf(v + fc_h_b[ng]);
        } else if (ng < 2048){
          int n = ng - 1024;
          m0[(size_t)rowg * 1024 + n] = tanhf(v + fc_m_b[n]);
        } else {
          int n = ng - 2048;
          xconst[(size_t)rowg * 4096 + n] += v;   // vpc wrote bias+vp first
        }
      }
}

// ---------- per-step: gates GEMM (all 4 gates per block) + fused LSTM cell ----------
__global__ __launch_bounds__(256) void k_gates(
    const bf16_t* __restrict__ h_in, const bf16_t* __restrict__ whh,
    const bf16_t* __restrict__ wlab, const bf16_t* __restrict__ labelb,
    const float* __restrict__ xconst,const float* __restrict__ w_ih,
    float* __restrict__ m, bf16_t* __restrict__ h_out, int t){
  __shared__ __align__(16) unsigned char smem[4 * 64 * 33 * 4]; // 33792 >= 27648 GEMM use
  bf16_t* sA = (bf16_t*)smem;
  bf16_t* sB = (bf16_t*)(smem + BM * LDSP * 2);
  float*  gbuf = (float*)smem;                 // reused after GEMM
  int tid = threadIdx.x;
  int cb = blockIdx.x, rb = blockIdx.y;        // cb: 32 col-blocks of H, rb: 8 row-blocks
  f32x4 acc[4][2] = {};
  int lane = tid & 63, w = tid >> 6;           // wave w owns gate w
  int nIter = (t > 0) ? 17 : 16;               // +1 K-tile for label input (t>=1)
  for (int kt = 0; kt < nIter; ++kt){
    if (kt < 16){
      stageA(sA, h_in + (size_t)(rb * 64) * 1024 + kt * 64, 1024, tid);
      #pragma unroll
      for (int i = 0; i < 4; ++i){
        int idx = tid + i * 256;
        int r = idx >> 3, v = idx & 7;
        int n = (r >> 5) * 1024 + cb * 32 + (r & 31);
        *reinterpret_cast<bf16x8*>(sB + r * LDSP + v * 8) =
          *reinterpret_cast<const bf16x8*>(whh + (size_t)n * 1024 + kt * 64 + v * 8);
      }
    } else {
      #pragma unroll
      for (int i = 0; i < 2; ++i){
        int idx = tid + i * 256;
        int r = idx >> 3, v = idx & 7;
        int rowg = rb * 64 + r;
        *reinterpret_cast<bf16x8*>(sA + r * LDSP + v * 8) =
          *reinterpret_cast<const bf16x8*>(labelb + ((size_t)rowg * 49 + (t - 1)) * 64 + v * 8);
      }
      #pragma unroll
      for (int i = 0; i < 4; ++i){
        int idx = tid + i * 256;
        int r = idx >> 3, v = idx & 7;
        int n = (r >> 5) * 1024 + cb * 32 + (r & 31);
        *reinterpret_cast<bf16x8*>(sB + r * LDSP + v * 8) =
          *reinterpret_cast<const bf16x8*>(wlab + (size_t)n * 64 + v * 8);
      }
    }
    __syncthreads();
    mma_tile(sA, sB, acc, lane, w);
    __syncthreads();
  }
  // epilogue: add xconst (+ begin column at t==0), exchange gates via LDS
  int lr = lane & 15, lg = lane >> 4;
  #pragma unroll
  for (int mi = 0; mi < 4; ++mi)
    #pragma unroll
    for (int ni = 0; ni < 2; ++ni)
      #pragma unroll
      for (int r = 0; r < 4; ++r){
        int cl = ni * 16 + lr;
        int ng = w * 1024 + cb * 32 + cl;
        int rl = mi * 16 + lg * 4 + r;
        int rowg = rb * 64 + rl;
        float v = acc[mi][ni][r] + xconst[(size_t)rowg * 4096 + ng];
        if (t == 0) v += w_ih[(size_t)ng * DINn + 1040];  // begin token weight
        gbuf[(w * 64 + rl) * 33 + cl] = v;
      }
  __syncthreads();
  // LSTM cell: each thread owns 8 cells (read i,f,g,o -> m,h update)
  #pragma unroll
  for (int rep = 0; rep < 8; ++rep){
    int cell = tid + rep * 256;          // 0..2047 over 64x32
    int rl = cell >> 5, cl = cell & 31;
    float gi = gbuf[(0 * 64 + rl) * 33 + cl];
    float gf = gbuf[(1 * 64 + rl) * 33 + cl];
    float gg = gbuf[(2 * 64 + rl) * 33 + cl];
    float go = gbuf[(3 * 64 + rl) * 33 + cl];
    int rowg = rb * 64 + rl, colg = cb * 32 + cl;
    size_t o = (size_t)rowg * 1024 + colg;
    float mo = m[o];
    float mn = sigm(gf) * mo + sigm(gi) * tanhf(gg);
    float hn = sigm(go) * tanhf(mn);
    m[o] = mn;
    h_out[o] = (bf16_t)hn;
  }
}

// ---------- per-step: out GEMM + activations + mask + scatter to 4 output slices ----------
__global__ __launch_bounds__(256) void k_out(
    const bf16_t* __restrict__ h, const bf16_t* __restrict__ fcwb,
    const float* __restrict__ fc_b, const int* __restrict__ length,
    float* __restrict__ out, int t){
  __shared__ __align__(16) unsigned char smem[(BM + 128) * LDSP * 2];
  bf16_t* sA = (bf16_t*)smem;
  bf16_t* sB = (bf16_t*)(smem + BM * LDSP * 2);
  int tid = threadIdx.x;
  int cb = blockIdx.x, rb = blockIdx.y;   // cb: 9 blocks cover 1090 (pad to 1152)
  f32x4 acc[4][2] = {};
  int lane = tid & 63, w = tid >> 6;
  for (int kt = 0; kt < 16; ++kt){
    stageA(sA, h + (size_t)(rb * 64) * 1024 + kt * 64, 1024, tid);
    #pragma unroll
    for (int i = 0; i < 4; ++i){
      int idx = tid + i * 256;
      int r = idx >> 3, v = idx & 7;
      int n = cb * 128 + r;
      bf16x8 val = {};
      if (n < NOn)
        val = *reinterpret_cast<const bf16x8*>(fcwb + (size_t)n * 1024 + kt * 64 + v * 8);
      *reinterpret_cast<bf16x8*>(sB + r * LDSP + v * 8) = val;
    }
    __syncthreads();
    mma_tile(sA, sB, acc, lane, w);
    __syncthreads();
  }
  int lr = lane & 15, lg = lane >> 4;
  #pragma unroll
  for (int mi = 0; mi < 4; ++mi)
    #pragma unroll
    for (int ni = 0; ni < 2; ++ni)
      #pragma unroll
      for (int r = 0; r < 4; ++r){
        int ng = cb * 128 + w * 32 + ni * 16 + lr;
        if (ng >= NOn) continue;
        int rowg = rb * 64 + mi * 16 + lg * 4 + r;
        float v = acc[mi][ni][r] + fc_b[ng];
        float mask = (t < length[rowg]) ? 1.0f : 0.0f;
        size_t tb = (size_t)t * 512 + rowg;
        if      (ng < 64)   out[tb * 64 + ng] = sigm(v) * mask;                        // lab
        else if (ng < 1088) out[(size_t)1572864 + tb * 1024 + (ng - 64)] = fmaxf(v, 0.f) * mask; // topic
        else if (ng == 1088) out[(size_t)26738688 + tb] = sigm(v) * mask;              // stop
        else                 out[(size_t)26763264 + tb] = __expf(v) * mask;            // temp
      }
}

extern "C" void kernel_launch(void* const* d_in, const int* in_sizes, int n_in,
                              void* d_out, int out_size, void* d_ws, size_t ws_size,
                              hipStream_t stream){
  const float* image  = (const float*)d_in[0];
  const float* vp     = (const float*)d_in[1];
  const float* label  = (const float*)d_in[2];
  const int*   length = (const int*)  d_in[3];
  const float* fc_h_w = (const float*)d_in[4];
  const float* fc_h_b = (const float*)d_in[5];
  const float* fc_m_w = (const float*)d_in[6];
  const float* fc_m_b = (const float*)d_in[7];
  const float* w_ih   = (const float*)d_in[8];
  const float* w_hh   = (const float*)d_in[9];
  const float* b_ih   = (const float*)d_in[10];
  const float* b_hh   = (const float*)d_in[11];
  const float* fc_w   = (const float*)d_in[12];
  const float* fc_b   = (const float*)d_in[13];
  float* out = (float*)d_out;

  char* ws = (char*)d_ws;
  bf16_t* imb    = (bf16_t*)(ws + 0);          // 512x1024 bf16
  bf16_t* h_a    = (bf16_t*)(ws + 1048576);    // 512x1024 bf16
  bf16_t* h_b    = (bf16_t*)(ws + 2097152);    // 512x1024 bf16
  float*  m      = (float*) (ws + 3145728);    // 512x1024 f32
  float*  xconst = (float*) (ws + 5242880);    // 512x4096 f32
  bf16_t* whhb   = (bf16_t*)(ws + 13631488);   // 4096x1024 bf16
  bf16_t* wimgb  = (bf16_t*)(ws + 22020096);   // 4096x1024 bf16
  bf16_t* wlabb  = (bf16_t*)(ws + 30408704);   // 4096x64 bf16
  bf16_t* fchwb  = (bf16_t*)(ws + 30932992);   // 1024x1024 bf16
  bf16_t* fcmwb  = (bf16_t*)(ws + 33030144);   // 1024x1024 bf16
  bf16_t* fcwb   = (bf16_t*)(ws + 35127296);   // 1090x1024 bf16
  bf16_t* labelb = (bf16_t*)(ws + 37360640);   // 512x49x64 bf16  (end ~40.6MB)

  k_mean   <<<dim3(512),  dim3(256), 0, stream>>>(image, imb);
  k_convert<<<dim3(2048), dim3(256), 0, stream>>>(w_hh, fc_h_w, fc_m_w, fc_w, label, w_ih,
                                                  whhb, fchwb, fcmwb, fcwb, labelb, wimgb, wlabb);
  k_vpc    <<<dim3(8192), dim3(256), 0, stream>>>(w_ih, vp, b_ih, b_hh, xconst);
  k_init_gemm<<<dim3(48, 8), dim3(256), 0, stream>>>(imb, fchwb, fcmwb, wimgb,
                                                     fc_h_b, fc_m_b, h_a, m, xconst);
  for (int t = 0; t < Tn; ++t){
    const bf16_t* hi = (t & 1) ? h_b : h_a;
    bf16_t*       ho = (t & 1) ? h_a : h_b;
    k_gates<<<dim3(32, 8), dim3(256), 0, stream>>>(hi, whhb, wlabb, labelb, xconst, w_ih, m, ho, t);
    k_out  <<<dim3(9, 8),  dim3(256), 0, stream>>>(ho, fcwb, fc_b, length, out, t);
  }
}